// Round 3
// baseline (277.934 us; speedup 1.0000x reference)
//
#include <hip/hip_runtime.h>

// modConv: y = demod(b,fo) * conv3x3(x * s(b,fi), w * w_scale)
// bf16 MFMA implicit GEMM (M=fo, N=pixels, K=fi, 9 taps accumulated).
// R8: x B-fragments loaded global->REGISTERS (x-tile had zero LDS reuse; its
//     LDS round-trip was pure overhead). w-tile stays in LDS (4x cross-wave
//     reuse), QUAD-buffered and staged 2 its ahead -> barrier#2 + lgkmcnt(0)
//     deleted: one raw s_barrier + one counted vmcnt(8) per iteration.
//     xf regs double-buffered with static names (no runtime-indexed arrays).
//     Geometry unchanged: 256-thr blocks, 128fo x 256px, XCD=b swizzle.

typedef __bf16 bf16_t;
typedef __bf16 bf16x8 __attribute__((ext_vector_type(8)));
typedef float floatx4 __attribute__((ext_vector_type(4)));

#define HW_ 4096
#define FCSCALE 0.04419417382415922f   /* 512^-0.5 */
#define WSCALE  0.014731391274719742f  /* (512*9)^-0.5 */

#define VMCNT(n) asm volatile("s_waitcnt vmcnt(" #n ")" ::: "memory")

__device__ __forceinline__ void gload_lds16(const bf16_t* g, bf16_t* l) {
  __builtin_amdgcn_global_load_lds(
      (const __attribute__((address_space(1))) void*)g,
      (__attribute__((address_space(3))) void*)l, 16, 0, 0);
}

// s[o] for o=b*512+fi: one wave per output, coalesced 2KB row read, shfl reduce
__global__ void k_style(const float* __restrict__ style, const float* __restrict__ fc_w,
                        const float* __restrict__ fc_b, float* __restrict__ s_out) {
  int o = blockIdx.x * 4 + (threadIdx.x >> 6);  // 0..4095
  int lane = threadIdx.x & 63;
  int b = o >> 9, fi = o & 511;
  const float4* st = (const float4*)(style + b * 512);
  const float4* fw = (const float4*)(fc_w + (size_t)fi * 512);
  float4 a0 = st[lane * 2],     w0 = fw[lane * 2];
  float4 a1 = st[lane * 2 + 1], w1 = fw[lane * 2 + 1];
  float acc = a0.x * w0.x + a0.y * w0.y + a0.z * w0.z + a0.w * w0.w
            + a1.x * w1.x + a1.y * w1.y + a1.z * w1.z + a1.w * w1.w;
#pragma unroll
  for (int d = 32; d >= 1; d >>= 1) acc += __shfl_xor(acc, d, 64);
  if (lane == 0) s_out[o] = acc * FCSCALE + fc_b[fi];
}

// wsq[fo][fi] = sum_tap (w*ws)^2 ; wt[tap][fi>>3][fo][fi&7] = bf16(w*ws)
__global__ void k_wsq_wt(const float* __restrict__ w, float* __restrict__ wsq,
                         bf16_t* __restrict__ wt) {
  int idx = blockIdx.x * 256 + threadIdx.x;     // fo*512+fi
  int fo = idx >> 9, fi = idx & 511;
  const float* wp = w + (size_t)idx * 9;
  float v[9], q = 0.f;
#pragma unroll
  for (int k = 0; k < 9; ++k) { v[k] = wp[k] * WSCALE; q += v[k] * v[k]; }
  wsq[idx] = q;
#pragma unroll
  for (int k = 0; k < 9; ++k)
    wt[((((size_t)k * 64) + (fi >> 3)) * 512 + fo) * 8 + (fi & 7)] = (bf16_t)v[k];
}

// d[o] = rsqrt(sum_fi wsq[fo][fi]*s[b][fi]^2 + eps): wave per output
__global__ void k_demod(const float* __restrict__ wsq, const float* __restrict__ s,
                        float* __restrict__ dcoef) {
  int o = blockIdx.x * 4 + (threadIdx.x >> 6);  // 0..4095 = b*512+fo
  int lane = threadIdx.x & 63;
  int b = o >> 9, fo = o & 511;
  const float4* wq = (const float4*)(wsq + (size_t)fo * 512);
  const float4* sp = (const float4*)(s + b * 512);
  float acc = 0.f;
#pragma unroll
  for (int i = 0; i < 2; ++i) {
    float4 q = wq[lane * 2 + i], sv = sp[lane * 2 + i];
    acc += q.x * sv.x * sv.x + q.y * sv.y * sv.y + q.z * sv.z * sv.z + q.w * sv.w * sv.w;
  }
#pragma unroll
  for (int d = 32; d >= 1; d >>= 1) acc += __shfl_xor(acc, d, 64);
  if (lane == 0) dcoef[o] = rsqrtf(acc + 1e-8f);
}

// xT[b][h][g][w][8] = bf16(x[b][g*8+j][h][w] * s)   (granule-major rows)
__global__ void k_modx(const float* __restrict__ x, const float* __restrict__ s,
                       bf16_t* __restrict__ xT) {
  __shared__ float tile[32][65];
  int b = blockIdx.z;
  int fi0 = blockIdx.x * 32;
  int h = blockIdx.y;                            // one image row (64 px)
  int t = threadIdx.x;
  int c4 = (t & 15) * 4, fr = t >> 4;            // float4 coalesced reads
#pragma unroll
  for (int i = 0; i < 2; ++i) {
    int fi_l = i * 16 + fr;
    float sv = s[b * 512 + fi0 + fi_l];
    float4 v = *(const float4*)(x + ((size_t)(b * 512 + fi0 + fi_l)) * HW_ + h * 64 + c4);
    tile[fi_l][c4] = v.x * sv; tile[fi_l][c4 + 1] = v.y * sv;
    tile[fi_l][c4 + 2] = v.z * sv; tile[fi_l][c4 + 3] = v.w * sv;
  }
  __syncthreads();
  int g_l = t >> 6, wcol = t & 63;               // write granule (g_l) x col
  bf16x8 vv;
#pragma unroll
  for (int j = 0; j < 8; ++j) vv[j] = (bf16_t)tile[g_l * 8 + j][wcol];
  *(bf16x8*)&xT[((((size_t)(b * 64 + h)) * 64 + (fi0 >> 3) + g_l) * 64 + wcol) * 8] = vv;
}

// Main: block = 128 fo x 256 px (4 rows h0..h0+3), 4 waves each 128 fo x 64 px.
// 144 its = 9 taps x 16 fi-chunks of 32.
//  - x B-frags: global -> regs (xfA/xfB dbuf), issued 1 it ahead. No LDS.
//  - w A-tile: LDS, quad-buffered (4 x 8KB), global_load_lds 2 its ahead.
//  - per it: {load_x(it+1); stage_w(it+2); vmcnt(8); s_barrier; sched_barrier;
//             compute(it)}  -- single barrier, counted vmcnt, no lgkmcnt drain.
//  vmcnt math (steady): in flight pre-wait = w(it)2+x(it)4+w(it+1)2+x(it+1)4
//  +w(it+2)2 = 14; vmcnt(8) drains exactly w(it)+x(it). Tail: 8,8,6,0.
__global__ __launch_bounds__(256, 2) void k_conv(const bf16_t* __restrict__ wt,
                                                 const bf16_t* __restrict__ xT,
                                                 const float* __restrict__ dcoef,
                                                 const bf16_t* __restrict__ zerobuf,
                                                 float* __restrict__ out) {
  __shared__ __align__(16) bf16_t wls[4 * 4 * 128 * 8];  // 4 bufs x [g][fo][8] 32KB

  int b   = blockIdx.x;                 // 0..7  (linear%8=b -> XCD-pinned batch)
  int foB = blockIdx.y;                 // 0..3
  int hq  = blockIdx.z;                 // 0..15 -> rows h0..h0+3
  int t = threadIdx.x;
  int wv = t >> 6, lane = t & 63, quad = lane >> 4, l16 = lane & 15;
  int h0 = hq * 4;
  int fo_l = t & 127, chunk_hi = t >> 7;

  const bf16_t* xTb = xT + (size_t)b * 64 * 64 * 64 * 8;   // [h][g][w][8]

  floatx4 acc[8][4];
#pragma unroll
  for (int i = 0; i < 8; ++i)
#pragma unroll
    for (int j = 0; j < 4; ++j) acc[i][j] = (floatx4){0.f, 0.f, 0.f, 0.f};

  // w A-tile staging: [tap][g][fo][8]; 2 gload_lds/thread; lanes=consec fo ->1KB
  auto stage_w = [&](int it, int pf) {
    int tap = it >> 4;
    int g0 = (it & 15) * 4;
#pragma unroll
    for (int itw = 0; itw < 2; ++itw) {
      int cw = itw * 2 + chunk_hi;
      gload_lds16(wt + ((((size_t)tap * 64) + g0 + cw) * 512 + foB * 128 + fo_l) * 8,
                  &wls[(size_t)pf * 4096 + (itw * 256 + wv * 64) * 8]);
    }
  };

  // x B-frags direct to regs: granule g0+quad, row h0+wv+kh-1, col j*16+l16+kw-1
  // per instr: 4 x 256B contiguous segments (one per quad) — fully coalesced.
  auto load_x = [&](int it, bf16x8* xf) {
    int tap = it >> 4;
    int g0 = (it & 15) * 4;
    int kh = tap / 3, kw = tap - kh * 3;
    int rg = h0 + wv + kh - 1;                   // wave-uniform source row
    bool rok = (unsigned)rg < 64u;
    const bf16_t* rowp = xTb + (((size_t)rg * 64 + g0 + quad) * 64) * 8;
#pragma unroll
    for (int j = 0; j < 4; ++j) {
      int c = j * 16 + l16 + kw - 1;             // per-lane source col
      const bf16_t* src = (rok && (unsigned)c < 64u) ? rowp + (size_t)c * 8
                                                     : zerobuf;
      xf[j] = *(const bf16x8*)src;
    }
  };

  auto compute = [&](int pc, const bf16x8* xf) {
    const bf16_t* wb = &wls[(size_t)pc * 4096];
    __builtin_amdgcn_s_setprio(1);
#pragma unroll
    for (int i = 0; i < 8; ++i) {
      bf16x8 afr = *(const bf16x8*)&wb[(quad * 128 + i * 16 + l16) * 8];
#pragma unroll
      for (int j = 0; j < 4; ++j)
        acc[i][j] = __builtin_amdgcn_mfma_f32_16x16x32_bf16(afr, xf[j], acc[i][j], 0, 0, 0);
    }
    __builtin_amdgcn_s_setprio(0);
  };

  bf16x8 xfA[4], xfB[4];

  // prologue (issue order w0, x0, w1 matches vmcnt math)
  stage_w(0, 0);
  load_x(0, xfA);
  stage_w(1, 1);

  for (int it = 0; it < 140; it += 2) {
    // even it: compute xfA, prefetch x->xfB, w->buf (it+2)&3
    load_x(it + 1, xfB);
    stage_w(it + 2, (it + 2) & 3);
    VMCNT(8);
    __builtin_amdgcn_s_barrier();
    __builtin_amdgcn_sched_barrier(0);
    compute(it & 3, xfA);
    // odd it+1
    load_x(it + 2, xfA);
    stage_w(it + 3, (it + 3) & 3);
    VMCNT(8);
    __builtin_amdgcn_s_barrier();
    __builtin_amdgcn_sched_barrier(0);
    compute((it + 1) & 3, xfB);
  }
  // it = 140
  load_x(141, xfB);
  stage_w(142, 2);
  VMCNT(8);
  __builtin_amdgcn_s_barrier();
  __builtin_amdgcn_sched_barrier(0);
  compute(0, xfA);
  // it = 141
  load_x(142, xfA);
  stage_w(143, 3);
  VMCNT(8);
  __builtin_amdgcn_s_barrier();
  __builtin_amdgcn_sched_barrier(0);
  compute(1, xfB);
  // it = 142 (no w-stage left)
  load_x(143, xfB);
  VMCNT(6);
  __builtin_amdgcn_s_barrier();
  __builtin_amdgcn_sched_barrier(0);
  compute(2, xfA);
  // it = 143
  VMCNT(0);
  __builtin_amdgcn_s_barrier();
  __builtin_amdgcn_sched_barrier(0);
  compute(3, xfB);

  // epilogue: C/D col=lane&15 (n=px), row=quad*4+reg (m=fo); scale by demod
  int h = h0 + wv;
#pragma unroll
  for (int i = 0; i < 8; ++i) {
#pragma unroll
    for (int rr = 0; rr < 4; ++rr) {
      int fo_g = foB * 128 + i * 16 + quad * 4 + rr;
      float dm = dcoef[b * 512 + fo_g];
      float* op = out + ((size_t)((b * 512 + fo_g) * 64 + h)) * 64;
#pragma unroll
      for (int j = 0; j < 4; ++j)
        op[j * 16 + l16] = acc[i][j][rr] * dm;
    }
  }
}

extern "C" void kernel_launch(void* const* d_in, const int* in_sizes, int n_in,
                              void* d_out, int out_size, void* d_ws, size_t ws_size,
                              hipStream_t stream) {
  const float* x     = (const float*)d_in[0];
  const float* style = (const float*)d_in[1];
  const float* w     = (const float*)d_in[2];
  const float* fc_w  = (const float*)d_in[3];
  const float* fc_b  = (const float*)d_in[4];
  float* out = (float*)d_out;
  char* ws = (char*)d_ws;

  float*  s       = (float*)(ws);                  // 16 KB
  float*  dcoef   = (float*)(ws + 16384);          // 16 KB
  float*  wsq     = (float*)(ws + 32768);          // 1 MB
  bf16_t* zerobuf = (bf16_t*)(ws + 1081344);       // 256 B of zeros
  bf16_t* wt      = (bf16_t*)(ws + 1081600);       // 4.5 MB  [tap][g][fo][8]
  bf16_t* xT      = (bf16_t*)(ws + 5800192);       // 32 MB   [b][h][g][w][8]

  hipMemsetAsync(zerobuf, 0, 256, stream);
  k_style<<<1024, 256, 0, stream>>>(style, fc_w, fc_b, s);
  k_wsq_wt<<<1024, 256, 0, stream>>>(w, wsq, wt);
  k_demod<<<1024, 256, 0, stream>>>(wsq, s, dcoef);
  k_modx<<<dim3(16, 64, 8), 256, 0, stream>>>(x, s, xT);
  // grid.x = b -> linear block id % 8 == b -> XCD-pinned batch slice
  k_conv<<<dim3(8, 4, 16), 256, 0, stream>>>(wt, xT, dcoef, zerobuf, out);
}

// Round 5
// 253.243 us; speedup vs baseline: 1.0975x; 1.0975x over previous
//
#include <hip/hip_runtime.h>

// modConv: y = demod(b,fo) * conv3x3(x * s(b,fi), w * w_scale)
// bf16 MFMA implicit GEMM (M=fo, N=pixels, K=fi, 9 taps accumulated).
// R10: R9 with the k_prep2 grid bug fixed (9216 blocks = 1024 demod + 8192
//     modx; R9's 10240 decoded to b=8 -> OOB -> abort).
//     (a) k_conv loop reorder it=(gchunk*9+tap): all 9 taps over one
//     x-granule-chunk consecutive -> x reuse L2-resident (was re-read 16 its
//     apart -> evicted -> 160MB HBM fetch vs 36.5MB unique).
//     (b) prep fused to 2 kernels (K1: wsq_wt|style|zero, K2: demod|modx).
//     Pipeline unchanged from R8: x->regs dbuf, w->LDS quad-buf, 1 raw
//     barrier + counted vmcnt(8) per it, setprio around MFMA.

typedef __bf16 bf16_t;
typedef __bf16 bf16x8 __attribute__((ext_vector_type(8)));
typedef float floatx4 __attribute__((ext_vector_type(4)));

#define HW_ 4096
#define FCSCALE 0.04419417382415922f   /* 512^-0.5 */
#define WSCALE  0.014731391274719742f  /* (512*9)^-0.5 */

#define VMCNT(n) asm volatile("s_waitcnt vmcnt(" #n ")" ::: "memory")

__device__ __forceinline__ void gload_lds16(const bf16_t* g, bf16_t* l) {
  __builtin_amdgcn_global_load_lds(
      (const __attribute__((address_space(1))) void*)g,
      (__attribute__((address_space(3))) void*)l, 16, 0, 0);
}

// ---- prep bodies (unchanged logic, parameterized block id) ----

__device__ __forceinline__ void style_body(int bid, int t,
    const float* __restrict__ style, const float* __restrict__ fc_w,
    const float* __restrict__ fc_b, float* __restrict__ s_out) {
  int o = bid * 4 + (t >> 6);                   // 0..4095 = b*512+fi
  int lane = t & 63;
  int b = o >> 9, fi = o & 511;
  const float4* st = (const float4*)(style + b * 512);
  const float4* fw = (const float4*)(fc_w + (size_t)fi * 512);
  float4 a0 = st[lane * 2],     w0 = fw[lane * 2];
  float4 a1 = st[lane * 2 + 1], w1 = fw[lane * 2 + 1];
  float acc = a0.x * w0.x + a0.y * w0.y + a0.z * w0.z + a0.w * w0.w
            + a1.x * w1.x + a1.y * w1.y + a1.z * w1.z + a1.w * w1.w;
#pragma unroll
  for (int d = 32; d >= 1; d >>= 1) acc += __shfl_xor(acc, d, 64);
  if (lane == 0) s_out[o] = acc * FCSCALE + fc_b[fi];
}

__device__ __forceinline__ void wsq_wt_body(int bid, int t,
    const float* __restrict__ w, float* __restrict__ wsq, bf16_t* __restrict__ wt) {
  int idx = bid * 256 + t;                      // fo*512+fi
  int fo = idx >> 9, fi = idx & 511;
  const float* wp = w + (size_t)idx * 9;
  float v[9], q = 0.f;
#pragma unroll
  for (int k = 0; k < 9; ++k) { v[k] = wp[k] * WSCALE; q += v[k] * v[k]; }
  wsq[idx] = q;
#pragma unroll
  for (int k = 0; k < 9; ++k)
    wt[((((size_t)k * 64) + (fi >> 3)) * 512 + fo) * 8 + (fi & 7)] = (bf16_t)v[k];
}

__device__ __forceinline__ void demod_body(int bid, int t,
    const float* __restrict__ wsq, const float* __restrict__ s,
    float* __restrict__ dcoef) {
  int o = bid * 4 + (t >> 6);                   // 0..4095 = b*512+fo
  int lane = t & 63;
  int b = o >> 9, fo = o & 511;
  const float4* wq = (const float4*)(wsq + (size_t)fo * 512);
  const float4* sp = (const float4*)(s + b * 512);
  float acc = 0.f;
#pragma unroll
  for (int i = 0; i < 2; ++i) {
    float4 q = wq[lane * 2 + i], sv = sp[lane * 2 + i];
    acc += q.x * sv.x * sv.x + q.y * sv.y * sv.y + q.z * sv.z * sv.z + q.w * sv.w * sv.w;
  }
#pragma unroll
  for (int d = 32; d >= 1; d >>= 1) acc += __shfl_xor(acc, d, 64);
  if (lane == 0) dcoef[o] = rsqrtf(acc + 1e-8f);
}

// K1: blocks 0..1023 -> wsq_wt, 1024..2047 -> style, 2048 -> zerobuf
__global__ void k_prep1(const float* __restrict__ style, const float* __restrict__ fc_w,
                        const float* __restrict__ fc_b, const float* __restrict__ w,
                        float* __restrict__ s_out, float* __restrict__ wsq,
                        bf16_t* __restrict__ wt, bf16_t* __restrict__ zerobuf) {
  int blk = blockIdx.x, t = threadIdx.x;
  if (blk < 1024) {
    wsq_wt_body(blk, t, w, wsq, wt);
  } else if (blk < 2048) {
    style_body(blk - 1024, t, style, fc_w, fc_b, s_out);
  } else {
    if (t < 128) zerobuf[t] = (bf16_t)0.f;      // 256 B
  }
}

// xT[b][h][g][w][8] = bf16(x[b][g*8+j][h][w] * s)   (granule-major rows)
__device__ __forceinline__ void modx_body(int fi0, int h, int b, int t,
    const float* __restrict__ x, const float* __restrict__ s,
    bf16_t* __restrict__ xT, float (*tile)[65]) {
  int c4 = (t & 15) * 4, fr = t >> 4;            // float4 coalesced reads
#pragma unroll
  for (int i = 0; i < 2; ++i) {
    int fi_l = i * 16 + fr;
    float sv = s[b * 512 + fi0 + fi_l];
    float4 v = *(const float4*)(x + ((size_t)(b * 512 + fi0 + fi_l)) * HW_ + h * 64 + c4);
    tile[fi_l][c4] = v.x * sv; tile[fi_l][c4 + 1] = v.y * sv;
    tile[fi_l][c4 + 2] = v.z * sv; tile[fi_l][c4 + 3] = v.w * sv;
  }
  __syncthreads();
  int g_l = t >> 6, wcol = t & 63;               // write granule (g_l) x col
  bf16x8 vv;
#pragma unroll
  for (int j = 0; j < 8; ++j) vv[j] = (bf16_t)tile[g_l * 8 + j][wcol];
  *(bf16x8*)&xT[((((size_t)(b * 64 + h)) * 64 + (fi0 >> 3) + g_l) * 64 + wcol) * 8] = vv;
}

// K2: blocks 0..1023 -> demod, 1024..9215 -> modx (m=blk-1024: b=m>>10,
// h=(m&1023)>>4, fi0=(m&15)*32; 8192 modx blocks total -> grid 9216)
__global__ void k_prep2(const float* __restrict__ x, const float* __restrict__ s,
                        const float* __restrict__ wsq, float* __restrict__ dcoef,
                        bf16_t* __restrict__ xT) {
  __shared__ float tile[32][65];
  int blk = blockIdx.x, t = threadIdx.x;
  if (blk < 1024) {
    demod_body(blk, t, wsq, s, dcoef);
  } else {
    int m = blk - 1024;                          // 0..8191
    int b = m >> 10, rem = m & 1023;             // b 0..7
    int h = rem >> 4, fi0 = (rem & 15) * 32;
    modx_body(fi0, h, b, t, x, s, xT, tile);
  }
}

// Main: block = 128 fo x 256 px (4 rows h0..h0+3), 4 waves each 128 fo x 64 px.
// 144 its = 16 fi-granule-chunks x 9 taps (gchunk OUTER, tap INNER -> the 9
// taps re-reading one x-footprint are consecutive -> L2-resident reuse).
//  - x B-frags: global -> regs (xfA/xfB dbuf), issued 1 it ahead. No LDS.
//  - w A-tile: LDS, quad-buffered (4 x 8KB), global_load_lds 2 its ahead.
//  - per it: {load_x(it+1); stage_w(it+2); vmcnt(8); s_barrier; sched_barrier;
//             compute(it)}  -- single barrier, counted vmcnt, no lgkmcnt drain.
//  vmcnt steady: in flight = w(it)2+x(it)4+w(it+1)2+x(it+1)4+w(it+2)2 = 14;
//  vmcnt(8) drains exactly w(it)+x(it). Tail: 8,8,6,0.
__global__ __launch_bounds__(256, 2) void k_conv(const bf16_t* __restrict__ wt,
                                                 const bf16_t* __restrict__ xT,
                                                 const float* __restrict__ dcoef,
                                                 const bf16_t* __restrict__ zerobuf,
                                                 float* __restrict__ out) {
  __shared__ __align__(16) bf16_t wls[4 * 4 * 128 * 8];  // 4 bufs x [g][fo][8] 32KB

  int b   = blockIdx.x;                 // 0..7  (linear%8=b -> XCD-pinned batch)
  int foB = blockIdx.y;                 // 0..3
  int hq  = blockIdx.z;                 // 0..15 -> rows h0..h0+3
  int t = threadIdx.x;
  int wv = t >> 6, lane = t & 63, quad = lane >> 4, l16 = lane & 15;
  int h0 = hq * 4;
  int fo_l = t & 127, chunk_hi = t >> 7;

  const bf16_t* xTb = xT + (size_t)b * 64 * 64 * 64 * 8;   // [h][g][w][8]

  floatx4 acc[8][4];
#pragma unroll
  for (int i = 0; i < 8; ++i)
#pragma unroll
    for (int j = 0; j < 4; ++j) acc[i][j] = (floatx4){0.f, 0.f, 0.f, 0.f};

  // it -> (gchunk, tap): gc = it/9 (exact via magic for it<1180), tap = it%9
  // w A-tile staging: [tap][g][fo][8]; 2 gload_lds/thread; lanes=consec fo ->1KB
  auto stage_w = [&](int it, int pf) {
    int gc = (it * 7282) >> 16;
    int tap = it - gc * 9;
    int g0 = gc * 4;
#pragma unroll
    for (int itw = 0; itw < 2; ++itw) {
      int cw = itw * 2 + chunk_hi;
      gload_lds16(wt + ((((size_t)tap * 64) + g0 + cw) * 512 + foB * 128 + fo_l) * 8,
                  &wls[(size_t)pf * 4096 + (itw * 256 + wv * 64) * 8]);
    }
  };

  // x B-frags direct to regs: granule g0+quad, row h0+wv+kh-1, col j*16+l16+kw-1
  // per instr: 4 x 256B contiguous segments (one per quad) — fully coalesced.
  auto load_x = [&](int it, bf16x8* xf) {
    int gc = (it * 7282) >> 16;
    int tap = it - gc * 9;
    int g0 = gc * 4;
    int kh = tap / 3, kw = tap - kh * 3;
    int rg = h0 + wv + kh - 1;                   // wave-uniform source row
    bool rok = (unsigned)rg < 64u;
    const bf16_t* rowp = xTb + (((size_t)rg * 64 + g0 + quad) * 64) * 8;
#pragma unroll
    for (int j = 0; j < 4; ++j) {
      int c = j * 16 + l16 + kw - 1;             // per-lane source col
      const bf16_t* src = (rok && (unsigned)c < 64u) ? rowp + (size_t)c * 8
                                                     : zerobuf;
      xf[j] = *(const bf16x8*)src;
    }
  };

  auto compute = [&](int pc, const bf16x8* xf) {
    const bf16_t* wb = &wls[(size_t)pc * 4096];
    __builtin_amdgcn_s_setprio(1);
#pragma unroll
    for (int i = 0; i < 8; ++i) {
      bf16x8 afr = *(const bf16x8*)&wb[(quad * 128 + i * 16 + l16) * 8];
#pragma unroll
      for (int j = 0; j < 4; ++j)
        acc[i][j] = __builtin_amdgcn_mfma_f32_16x16x32_bf16(afr, xf[j], acc[i][j], 0, 0, 0);
    }
    __builtin_amdgcn_s_setprio(0);
  };

  bf16x8 xfA[4], xfB[4];

  // prologue (issue order w0, x0, w1 matches vmcnt math)
  stage_w(0, 0);
  load_x(0, xfA);
  stage_w(1, 1);

  for (int it = 0; it < 140; it += 2) {
    // even it: compute xfA, prefetch x->xfB, w->buf (it+2)&3
    load_x(it + 1, xfB);
    stage_w(it + 2, (it + 2) & 3);
    VMCNT(8);
    __builtin_amdgcn_s_barrier();
    __builtin_amdgcn_sched_barrier(0);
    compute(it & 3, xfA);
    // odd it+1
    load_x(it + 2, xfA);
    stage_w(it + 3, (it + 3) & 3);
    VMCNT(8);
    __builtin_amdgcn_s_barrier();
    __builtin_amdgcn_sched_barrier(0);
    compute((it + 1) & 3, xfB);
  }
  // it = 140
  load_x(141, xfB);
  stage_w(142, 2);
  VMCNT(8);
  __builtin_amdgcn_s_barrier();
  __builtin_amdgcn_sched_barrier(0);
  compute(0, xfA);
  // it = 141
  load_x(142, xfA);
  stage_w(143, 3);
  VMCNT(8);
  __builtin_amdgcn_s_barrier();
  __builtin_amdgcn_sched_barrier(0);
  compute(1, xfB);
  // it = 142 (no w-stage left)
  load_x(143, xfB);
  VMCNT(6);
  __builtin_amdgcn_s_barrier();
  __builtin_amdgcn_sched_barrier(0);
  compute(2, xfA);
  // it = 143
  VMCNT(0);
  __builtin_amdgcn_s_barrier();
  __builtin_amdgcn_sched_barrier(0);
  compute(3, xfB);

  // epilogue: C/D col=lane&15 (n=px), row=quad*4+reg (m=fo); scale by demod
  int h = h0 + wv;
#pragma unroll
  for (int i = 0; i < 8; ++i) {
#pragma unroll
    for (int rr = 0; rr < 4; ++rr) {
      int fo_g = foB * 128 + i * 16 + quad * 4 + rr;
      float dm = dcoef[b * 512 + fo_g];
      float* op = out + ((size_t)((b * 512 + fo_g) * 64 + h)) * 64;
#pragma unroll
      for (int j = 0; j < 4; ++j)
        op[j * 16 + l16] = acc[i][j][rr] * dm;
    }
  }
}

extern "C" void kernel_launch(void* const* d_in, const int* in_sizes, int n_in,
                              void* d_out, int out_size, void* d_ws, size_t ws_size,
                              hipStream_t stream) {
  const float* x     = (const float*)d_in[0];
  const float* style = (const float*)d_in[1];
  const float* w     = (const float*)d_in[2];
  const float* fc_w  = (const float*)d_in[3];
  const float* fc_b  = (const float*)d_in[4];
  float* out = (float*)d_out;
  char* ws = (char*)d_ws;

  float*  s       = (float*)(ws);                  // 16 KB
  float*  dcoef   = (float*)(ws + 16384);          // 16 KB
  float*  wsq     = (float*)(ws + 32768);          // 1 MB
  bf16_t* zerobuf = (bf16_t*)(ws + 1081344);       // 256 B of zeros
  bf16_t* wt      = (bf16_t*)(ws + 1081600);       // 4.5 MB  [tap][g][fo][8]
  bf16_t* xT      = (bf16_t*)(ws + 5800192);       // 32 MB   [b][h][g][w][8]

  k_prep1<<<2049, 256, 0, stream>>>(style, fc_w, fc_b, w, s, wsq, wt, zerobuf);
  k_prep2<<<9216, 256, 0, stream>>>(x, s, wsq, dcoef, xT);
  // grid.x = b -> linear block id % 8 == b -> XCD-pinned batch slice
  k_conv<<<dim3(8, 4, 16), 256, 0, stream>>>(wt, xT, dcoef, zerobuf, out);
}

// Round 6
// 235.416 us; speedup vs baseline: 1.1806x; 1.0757x over previous
//
#include <hip/hip_runtime.h>

// modConv: y = demod(b,fo) * conv3x3(x * s(b,fi), w * w_scale)
// bf16 MFMA implicit GEMM (M=fo, N=pixels, K=fi, 9 taps accumulated).
// R11: gc-outer / 9-phase-unrolled schedule. x window (6 rows x 4 granules x
//     64 cols = 24KB) staged ONCE per gc into LDS (dbuf), taps read shifted
//     B-frags via ds_read_b128 (was: per-tap L2 reads, 9x re-traffic, 1-it
//     lead). x staged in 3 parts at phases 1-3 of the PREVIOUS gc (>=2-phase
//     slack); w dbuf staged 1 phase ahead after the barrier. Counted vmcnt
//     per phase from in-order VMEM retirement (N = loads issued after the
//     needed w-tile): phases 2-4 -> 2, else 0. Col halo via LDS zero-slot,
//     row halo via zerobuf staging. kh/kw compile-time per phase.

typedef __bf16 bf16_t;
typedef __bf16 bf16x8 __attribute__((ext_vector_type(8)));
typedef float floatx4 __attribute__((ext_vector_type(4)));

#define HW_ 4096
#define FCSCALE 0.04419417382415922f   /* 512^-0.5 */
#define WSCALE  0.014731391274719742f  /* (512*9)^-0.5 */

#define VMCNT(n) asm volatile("s_waitcnt vmcnt(" #n ")" ::: "memory")

__device__ __forceinline__ void gload_lds16(const bf16_t* g, bf16_t* l) {
  __builtin_amdgcn_global_load_lds(
      (const __attribute__((address_space(1))) void*)g,
      (__attribute__((address_space(3))) void*)l, 16, 0, 0);
}

// ---- prep bodies (R10-verified) ----

__device__ __forceinline__ void style_body(int bid, int t,
    const float* __restrict__ style, const float* __restrict__ fc_w,
    const float* __restrict__ fc_b, float* __restrict__ s_out) {
  int o = bid * 4 + (t >> 6);                   // 0..4095 = b*512+fi
  int lane = t & 63;
  int b = o >> 9, fi = o & 511;
  const float4* st = (const float4*)(style + b * 512);
  const float4* fw = (const float4*)(fc_w + (size_t)fi * 512);
  float4 a0 = st[lane * 2],     w0 = fw[lane * 2];
  float4 a1 = st[lane * 2 + 1], w1 = fw[lane * 2 + 1];
  float acc = a0.x * w0.x + a0.y * w0.y + a0.z * w0.z + a0.w * w0.w
            + a1.x * w1.x + a1.y * w1.y + a1.z * w1.z + a1.w * w1.w;
#pragma unroll
  for (int d = 32; d >= 1; d >>= 1) acc += __shfl_xor(acc, d, 64);
  if (lane == 0) s_out[o] = acc * FCSCALE + fc_b[fi];
}

__device__ __forceinline__ void wsq_wt_body(int bid, int t,
    const float* __restrict__ w, float* __restrict__ wsq, bf16_t* __restrict__ wt) {
  int idx = bid * 256 + t;                      // fo*512+fi
  int fo = idx >> 9, fi = idx & 511;
  const float* wp = w + (size_t)idx * 9;
  float v[9], q = 0.f;
#pragma unroll
  for (int k = 0; k < 9; ++k) { v[k] = wp[k] * WSCALE; q += v[k] * v[k]; }
  wsq[idx] = q;
#pragma unroll
  for (int k = 0; k < 9; ++k)
    wt[((((size_t)k * 64) + (fi >> 3)) * 512 + fo) * 8 + (fi & 7)] = (bf16_t)v[k];
}

__device__ __forceinline__ void demod_body(int bid, int t,
    const float* __restrict__ wsq, const float* __restrict__ s,
    float* __restrict__ dcoef) {
  int o = bid * 4 + (t >> 6);                   // 0..4095 = b*512+fo
  int lane = t & 63;
  int b = o >> 9, fo = o & 511;
  const float4* wq = (const float4*)(wsq + (size_t)fo * 512);
  const float4* sp = (const float4*)(s + b * 512);
  float acc = 0.f;
#pragma unroll
  for (int i = 0; i < 2; ++i) {
    float4 q = wq[lane * 2 + i], sv = sp[lane * 2 + i];
    acc += q.x * sv.x * sv.x + q.y * sv.y * sv.y + q.z * sv.z * sv.z + q.w * sv.w * sv.w;
  }
#pragma unroll
  for (int d = 32; d >= 1; d >>= 1) acc += __shfl_xor(acc, d, 64);
  if (lane == 0) dcoef[o] = rsqrtf(acc + 1e-8f);
}

// K1: blocks 0..1023 -> wsq_wt, 1024..2047 -> style, 2048 -> zerobuf
__global__ void k_prep1(const float* __restrict__ style, const float* __restrict__ fc_w,
                        const float* __restrict__ fc_b, const float* __restrict__ w,
                        float* __restrict__ s_out, float* __restrict__ wsq,
                        bf16_t* __restrict__ wt, bf16_t* __restrict__ zerobuf) {
  int blk = blockIdx.x, t = threadIdx.x;
  if (blk < 1024) {
    wsq_wt_body(blk, t, w, wsq, wt);
  } else if (blk < 2048) {
    style_body(blk - 1024, t, style, fc_w, fc_b, s_out);
  } else {
    if (t < 128) zerobuf[t] = (bf16_t)0.f;      // 256 B
  }
}

// xT[b][h][g][w][8] = bf16(x[b][g*8+j][h][w] * s)   (granule-major rows)
__device__ __forceinline__ void modx_body(int fi0, int h, int b, int t,
    const float* __restrict__ x, const float* __restrict__ s,
    bf16_t* __restrict__ xT, float (*tile)[65]) {
  int c4 = (t & 15) * 4, fr = t >> 4;            // float4 coalesced reads
#pragma unroll
  for (int i = 0; i < 2; ++i) {
    int fi_l = i * 16 + fr;
    float sv = s[b * 512 + fi0 + fi_l];
    float4 v = *(const float4*)(x + ((size_t)(b * 512 + fi0 + fi_l)) * HW_ + h * 64 + c4);
    tile[fi_l][c4] = v.x * sv; tile[fi_l][c4 + 1] = v.y * sv;
    tile[fi_l][c4 + 2] = v.z * sv; tile[fi_l][c4 + 3] = v.w * sv;
  }
  __syncthreads();
  int g_l = t >> 6, wcol = t & 63;               // write granule (g_l) x col
  bf16x8 vv;
#pragma unroll
  for (int j = 0; j < 8; ++j) vv[j] = (bf16_t)tile[g_l * 8 + j][wcol];
  *(bf16x8*)&xT[((((size_t)(b * 64 + h)) * 64 + (fi0 >> 3) + g_l) * 64 + wcol) * 8] = vv;
}

// K2: blocks 0..1023 -> demod, 1024..9215 -> modx
__global__ void k_prep2(const float* __restrict__ x, const float* __restrict__ s,
                        const float* __restrict__ wsq, float* __restrict__ dcoef,
                        bf16_t* __restrict__ xT) {
  __shared__ float tile[32][65];
  int blk = blockIdx.x, t = threadIdx.x;
  if (blk < 1024) {
    demod_body(blk, t, wsq, s, dcoef);
  } else {
    int m = blk - 1024;                          // 0..8191
    int b = m >> 10, rem = m & 1023;             // b 0..7
    int h = rem >> 4, fi0 = (rem & 15) * 32;
    modx_body(fi0, h, b, t, x, s, xT, tile);
  }
}

// ---- main conv ----
// Shared layout (bf16 elems): [0,24576)  = x bufs: 2 x [6 r][4 g][64 c][8 fi]
//                             [24576,32768) = w bufs: 2 x [4 g][128 fo][8 fi]
//                             [32768,32776) = zero slot (16B)
// Block = 128 fo x 256 px (4 rows), 4 waves. gc loop (16 chunks of 32 fi),
// 9 tap-phases unrolled. Phase P: {VMCNT(N_P); s_barrier; sched_barrier;
//   stage_w(it+1); [stage_x part if P in 1..3]; ds_read frags; 32 MFMA}.
__global__ __launch_bounds__(256, 2) void k_conv(const bf16_t* __restrict__ wt,
                                                 const bf16_t* __restrict__ xT,
                                                 const float* __restrict__ dcoef,
                                                 const bf16_t* __restrict__ zerobuf,
                                                 float* __restrict__ out) {
  __shared__ __align__(16) bf16_t sh[32776];     // 65552 B

  int b   = blockIdx.x;                 // 0..7  (linear%8=b -> XCD-pinned batch)
  int foB = blockIdx.y;                 // 0..3
  int hq  = blockIdx.z;                 // 0..15 -> rows h0..h0+3
  int t = threadIdx.x;
  int wv = t >> 6, lane = t & 63, quad = lane >> 4, l16 = lane & 15;
  int h0 = hq * 4;
  int fo_l = t & 127, chunk_hi = t >> 7;

  const bf16_t* xTb = xT + (size_t)b * 64 * 64 * 64 * 8;   // [h][g][w][8]
  const bf16_t* zslotp = &sh[32768];
  int XRB = ((wv * 4 + quad) * 64 + l16) * 8;    // per-lane x-frag base (elems)

  floatx4 acc[8][4];
#pragma unroll
  for (int i = 0; i < 8; ++i)
#pragma unroll
    for (int j = 0; j < 4; ++j) acc[i][j] = (floatx4){0.f, 0.f, 0.f, 0.f};

  // ---- prologue: zero slot, stage x(gc=0)->buf0 (6 spans/wave), w(it=0)->buf0
  if (t < 8) sh[32768 + t] = (bf16_t)0.f;
#pragma unroll
  for (int k = 0; k < 3; ++k)
#pragma unroll
    for (int u = 0; u < 2; ++u) {
      int s = k * 8 + wv * 2 + u;                // 0..23
      int r = s >> 2, g = s & 3;
      int rg = h0 + r - 1;
      const bf16_t* src = ((unsigned)rg < 64u)
          ? xTb + (((size_t)rg * 64 + g) * 64 + lane) * 8
          : zerobuf;
      gload_lds16(src, &sh[((r * 4 + g) * 64) * 8]);
    }
#pragma unroll
  for (int itw = 0; itw < 2; ++itw) {
    int cw = itw * 2 + chunk_hi;
    gload_lds16(wt + (((size_t)cw) * 512 + foB * 128 + fo_l) * 8,
                &sh[24576 + (itw * 256 + wv * 64) * 8]);
  }
  VMCNT(0);
  __syncthreads();                               // drains lgkm (zslot) too

#define PHASE(P, NW, XPART, GCLAST)                                            \
  do {                                                                         \
    VMCNT(NW);                                                                 \
    __builtin_amdgcn_s_barrier();                                              \
    __builtin_amdgcn_sched_barrier(0);                                         \
    if (!(GCLAST) || (P) < 8) { /* stage w(it+1) -> buf ((gc9+P+1)&1) */       \
      const int TAP1 = ((P) + 1) % 9;                                          \
      int g01 = ((P) == 8) ? (gc + 1) * 4 : gc * 4;                            \
      int wb1 = ((gc9 + (P) + 1) & 1) * 4096;                                  \
      _Pragma("unroll")                                                        \
      for (int itw = 0; itw < 2; ++itw) {                                      \
        int cw = itw * 2 + chunk_hi;                                           \
        gload_lds16(wt + ((((size_t)TAP1 * 64) + g01 + cw) * 512               \
                          + foB * 128 + fo_l) * 8,                             \
                    &sh[24576 + wb1 + (itw * 256 + wv * 64) * 8]);             \
      }                                                                        \
    }                                                                          \
    if ((XPART) >= 0 && !(GCLAST)) { /* stage x(gc+1) part -> buf ((gc+1)&1) */\
      int xb1 = ((gc + 1) & 1) * 12288;                                        \
      int g0n = (gc + 1) * 4;                                                  \
      _Pragma("unroll")                                                        \
      for (int u = 0; u < 2; ++u) {                                            \
        int s = (XPART) * 8 + wv * 2 + u;                                      \
        int r = s >> 2, g = s & 3;                                             \
        int rg = h0 + r - 1;                                                   \
        const bf16_t* src = ((unsigned)rg < 64u)                               \
            ? xTb + (((size_t)rg * 64 + g0n + g) * 64 + lane) * 8              \
            : zerobuf;                                                         \
        gload_lds16(src, &sh[xb1 + ((r * 4 + g) * 64) * 8]);                   \
      }                                                                        \
    }                                                                          \
    { /* compute(it = gc9+P), tap constants */                                 \
      const int KH = (P) / 3, KW = (P) % 3;                                    \
      int xb = (gc & 1) * 12288;                                               \
      int wb = ((gc9 + (P)) & 1) * 4096;                                       \
      bf16x8 bfr[4];                                                           \
      _Pragma("unroll")                                                        \
      for (int j = 0; j < 4; ++j) {                                            \
        const bf16_t* ap = &sh[xb + XRB + KH * 2048 + (j * 16 + KW - 1) * 8];  \
        if (KW == 0 && (j) == 0) { if (l16 == 0)  ap = zslotp; }               \
        if (KW == 2 && (j) == 3) { if (l16 == 15) ap = zslotp; }               \
        bfr[j] = *(const bf16x8*)ap;                                           \
      }                                                                        \
      __builtin_amdgcn_s_setprio(1);                                           \
      _Pragma("unroll")                                                        \
      for (int i = 0; i < 8; ++i) {                                            \
        bf16x8 afr = *(const bf16x8*)&sh[24576 + wb                            \
                                         + (quad * 128 + i * 16 + l16) * 8];   \
        _Pragma("unroll")                                                      \
        for (int j = 0; j < 4; ++j)                                            \
          acc[i][j] = __builtin_amdgcn_mfma_f32_16x16x32_bf16(                 \
              afr, bfr[j], acc[i][j], 0, 0, 0);                                \
      }                                                                        \
      __builtin_amdgcn_s_setprio(0);                                           \
    }                                                                          \
  } while (0)

  for (int gc = 0; gc < 15; ++gc) {
    int gc9 = gc * 9;
    PHASE(0, 0, -1, false);
    PHASE(1, 0,  0, false);
    PHASE(2, 2,  1, false);
    PHASE(3, 2,  2, false);
    PHASE(4, 2, -1, false);
    PHASE(5, 0, -1, false);
    PHASE(6, 0, -1, false);
    PHASE(7, 0, -1, false);
    PHASE(8, 0, -1, false);
  }
  {
    int gc = 15, gc9 = 135;
    PHASE(0, 0, -1, true);
    PHASE(1, 0, -1, true);
    PHASE(2, 0, -1, true);
    PHASE(3, 0, -1, true);
    PHASE(4, 0, -1, true);
    PHASE(5, 0, -1, true);
    PHASE(6, 0, -1, true);
    PHASE(7, 0, -1, true);
    PHASE(8, 0, -1, true);
  }
#undef PHASE

  // epilogue: C/D col=lane&15 (n=px), row=quad*4+reg (m=fo); scale by demod
  int h = h0 + wv;
#pragma unroll
  for (int i = 0; i < 8; ++i) {
#pragma unroll
    for (int rr = 0; rr < 4; ++rr) {
      int fo_g = foB * 128 + i * 16 + quad * 4 + rr;
      float dm = dcoef[b * 512 + fo_g];
      float* op = out + ((size_t)((b * 512 + fo_g) * 64 + h)) * 64;
#pragma unroll
      for (int j = 0; j < 4; ++j)
        op[j * 16 + l16] = acc[i][j][rr] * dm;
    }
  }
}

extern "C" void kernel_launch(void* const* d_in, const int* in_sizes, int n_in,
                              void* d_out, int out_size, void* d_ws, size_t ws_size,
                              hipStream_t stream) {
  const float* x     = (const float*)d_in[0];
  const float* style = (const float*)d_in[1];
  const float* w     = (const float*)d_in[2];
  const float* fc_w  = (const float*)d_in[3];
  const float* fc_b  = (const float*)d_in[4];
  float* out = (float*)d_out;
  char* ws = (char*)d_ws;

  float*  s       = (float*)(ws);                  // 16 KB
  float*  dcoef   = (float*)(ws + 16384);          // 16 KB
  float*  wsq     = (float*)(ws + 32768);          // 1 MB
  bf16_t* zerobuf = (bf16_t*)(ws + 1081344);       // 256 B of zeros
  bf16_t* wt      = (bf16_t*)(ws + 1081600);       // 4.5 MB  [tap][g][fo][8]
  bf16_t* xT      = (bf16_t*)(ws + 5800192);       // 32 MB   [b][h][g][w][8]

  k_prep1<<<2049, 256, 0, stream>>>(style, fc_w, fc_b, w, s, wsq, wt, zerobuf);
  k_prep2<<<9216, 256, 0, stream>>>(x, s, wsq, dcoef, xT);
  // grid.x = b -> linear block id % 8 == b -> XCD-pinned batch slice
  k_conv<<<dim3(8, 4, 16), 256, 0, stream>>>(wt, xT, dcoef, zerobuf, out);
}